// Round 2
// baseline (185.530 us; speedup 1.0000x reference)
//
#include <hip/hip_runtime.h>
#include <stdint.h>

#define K_NODES 14
#define C_DIM   512
#define OUT_DIM 512
#define N_EDGE  78

typedef float  f32x4  __attribute__((ext_vector_type(4)));
typedef __bf16 bf16x8 __attribute__((ext_vector_type(8)));

__device__ __forceinline__ unsigned short f2bf(float f) {
    unsigned int u = __builtin_bit_cast(unsigned int, f);
    unsigned int r = (u + 0x7fffu + ((u >> 16) & 1u)) >> 16;  // RNE
    return (unsigned short)r;
}
__device__ __forceinline__ float bf2f(unsigned short s) {
    return __builtin_bit_cast(float, (unsigned int)s << 16);
}

// async 16B global -> LDS (LDS dest is wave-uniform base; HW adds lane*16)
__device__ __forceinline__ void async16(const void* g, void* l) {
    __builtin_amdgcn_global_load_lds(
        (const __attribute__((address_space(1))) unsigned int*)g,
        (__attribute__((address_space(3))) unsigned int*)l, 16, 0, 0);
}

// ------- Kernel 1: per-channel stats partials + x->bf16 + weights->bf16 ----
__global__ __launch_bounds__(1024) void stats_partial(
    const float* __restrict__ x, float* __restrict__ part,
    unsigned short* __restrict__ xbf,
    const float* __restrict__ Wm, const float* __restrict__ Wo,
    unsigned short* __restrict__ wmbf, unsigned short* __restrict__ wobf)
{
    int t  = threadIdx.x;
    int q  = t & 127;           // channel quad: channels 4q..4q+3
    int sn = t >> 7;            // sample slot 0..7
    int n  = blockIdx.x * 8 + sn;
    size_t base = (size_t)n * K_NODES * C_DIM + q * 4;

    f32x4 g = *(const f32x4*)(x + base + 13 * C_DIM);
    ushort4 gb; gb.x=f2bf(g.x); gb.y=f2bf(g.y); gb.z=f2bf(g.z); gb.w=f2bf(g.w);
    *(ushort4*)(xbf + base + 13 * C_DIM) = gb;

    float S10=0,S11=0,S12=0,S13=0, S20=0,S21=0,S22=0,S23=0, Sw0=0,Sw1=0,Sw2=0,Sw3=0;
    #pragma unroll
    for (int k = 0; k < 13; ++k) {
        f32x4 v = *(const f32x4*)(x + base + k * C_DIM);
        ushort4 vb; vb.x=f2bf(v.x); vb.y=f2bf(v.y); vb.z=f2bf(v.z); vb.w=f2bf(v.w);
        *(ushort4*)(xbf + base + k * C_DIM) = vb;
        float wk = (float)(12 - 2 * k);
        float d0=fabsf(v.x-g.x), d1=fabsf(v.y-g.y), d2=fabsf(v.z-g.z), d3=fabsf(v.w-g.w);
        S10+=d0; S11+=d1; S12+=d2; S13+=d3;
        S20+=d0*d0; S21+=d1*d1; S22+=d2*d2; S23+=d3*d3;
        Sw0+=wk*d0; Sw1+=wk*d1; Sw2+=wk*d2; Sw3+=wk*d3;
    }
    f32x4 as = (f32x4){15.f*Sw0, 15.f*Sw1, 15.f*Sw2, 15.f*Sw3};
    f32x4 aq = (f32x4){225.f*(13.f*S20 - S10*S10), 225.f*(13.f*S21 - S11*S11),
                       225.f*(13.f*S22 - S12*S12), 225.f*(13.f*S23 - S13*S13)};

    __shared__ f32x4 redS[8][128];
    __shared__ f32x4 redQ[8][128];
    redS[sn][q] = as;
    redQ[sn][q] = aq;
    __syncthreads();
    if (sn == 0) {
        f32x4 s = redS[0][q], z = redQ[0][q];
        #pragma unroll
        for (int r = 1; r < 8; ++r) { s += redS[r][q]; z += redQ[r][q]; }
        *(f32x4*)(part + (size_t)blockIdx.x * 1024 + q * 4)       = s;
        *(f32x4*)(part + (size_t)blockIdx.x * 1024 + 512 + q * 4) = z;
    }
    int i0 = blockIdx.x * 1024 + t;
    wmbf[i0] = f2bf(Wm[i0]);
    wobf[i0] = f2bf(Wo[i0]);
}

// ---------------- Kernel 2: finalize stats -> u[c], bpart[8] ---------------
__global__ __launch_bounds__(256) void finalize_stats(
    const float* __restrict__ part, float inv_ne,
    const float* __restrict__ gamma, const float* __restrict__ beta,
    const float* __restrict__ wdir, float* __restrict__ u, float* __restrict__ bpart)
{
    int lane = threadIdx.x & 63;
    int wv   = threadIdx.x >> 6;        // 0..3
    int c    = blockIdx.x * 64 + lane;  // channel
    float s = 0.f, q = 0.f;
    #pragma unroll 8
    for (int r = wv; r < 256; r += 4) {
        s += part[(size_t)r * 1024 + c];
        q += part[(size_t)r * 1024 + 512 + c];
    }
    __shared__ float shs[4][64], shq[4][64];
    shs[wv][lane] = s; shq[wv][lane] = q;
    __syncthreads();
    if (wv == 0) {
        s = shs[0][lane] + shs[1][lane] + shs[2][lane] + shs[3][lane];
        q = shq[0][lane] + shq[1][lane] + shq[2][lane] + shq[3][lane];
        float mean = s * inv_ne;
        float var  = q * inv_ne - mean * mean;
        float sc   = gamma[c] / sqrtf(var + 1e-5f);
        u[c] = sc * wdir[c];
        float b = (beta[c] - mean * sc) * wdir[c];
        #pragma unroll
        for (int off = 1; off < 64; off <<= 1) b += __shfl_xor(b, off, 64);
        if (lane == 0) bpart[blockIdx.x] = b;
    }
}

// ---------------- Kernel 3: per-n gates + adjacency + agg ------------------
__global__ __launch_bounds__(256) void fuse_graph(
    const unsigned short* __restrict__ xbf, const float* __restrict__ adj,
    const int* __restrict__ ei, const int* __restrict__ ej,
    const float* __restrict__ u, const float* __restrict__ bpart,
    unsigned short* __restrict__ aggbf)
{
    __shared__ float WL[2][196];
    __shared__ float Dp[2][2][13];
    __shared__ float invL[2][14];
    int wv = threadIdx.x >> 6, lane = threadIdx.x & 63;
    int sp = wv >> 1;          // sample slot 0..1
    int h  = wv & 1;           // channel half 0..1
    int n  = blockIdx.x * 2 + sp;
    size_t base = (size_t)n * K_NODES * C_DIM + h * 256 + lane * 4;

    float xf[K_NODES][4];
    #pragma unroll
    for (int k = 0; k < K_NODES; ++k) {
        uint2 raw = *(const uint2*)(xbf + base + k * C_DIM);
        xf[k][0]=bf2f(raw.x&0xffff); xf[k][1]=bf2f(raw.x>>16);
        xf[k][2]=bf2f(raw.y&0xffff); xf[k][3]=bf2f(raw.y>>16);
    }
    f32x4 uv = *(const f32x4*)(u + h * 256 + lane * 4);

    #pragma unroll
    for (int k = 0; k < 13; ++k) {
        float p = fabsf(xf[k][0]-xf[13][0])*uv.x + fabsf(xf[k][1]-xf[13][1])*uv.y
                + fabsf(xf[k][2]-xf[13][2])*uv.z + fabsf(xf[k][3]-xf[13][3])*uv.w;
        #pragma unroll
        for (int off = 1; off < 64; off <<= 1) p += __shfl_xor(p, off, 64);
        if (lane == 0) Dp[sp][h][k] = p;
    }
    __syncthreads();

    if (h == 0) {
        float bc = 0.f;
        #pragma unroll
        for (int b8 = 0; b8 < 8; ++b8) bc += bpart[b8];
        for (int e = lane; e < N_EDGE; e += 64) {
            int ii = ei[e], jj = ej[e];
            float Di = Dp[sp][0][ii] + Dp[sp][1][ii];
            float Dj = Dp[sp][0][jj] + Dp[sp][1][jj];
            float z = 4.0f * (15.f * (Di - Dj) + bc);
            float a = 1.f / (1.f + expf(-z));
            WL[sp][ii * K_NODES + jj] = adj[ii * K_NODES + jj] * (2.f * a);
            WL[sp][jj * K_NODES + ii] = adj[jj * K_NODES + ii] * (2.f * (1.f - a));
        }
    } else {
        for (int idx = lane; idx < K_NODES * K_NODES; idx += 64) {
            int i = idx / K_NODES, j = idx - i * K_NODES;
            if (i == j || i == 13 || j == 13) WL[sp][idx] = adj[idx];
        }
    }
    __syncthreads();
    if (h == 0 && lane < K_NODES) {
        float s = 0.f;
        #pragma unroll
        for (int j = 0; j < K_NODES; ++j) s += fabsf(WL[sp][lane * K_NODES + j]);
        invL[sp][lane] = 1.f / fmaxf(s, 1e-12f);
    }
    __syncthreads();

    #pragma unroll
    for (int i = 0; i < K_NODES; ++i) {
        float s0=0.f,s1=0.f,s2=0.f,s3=0.f;
        #pragma unroll
        for (int j = 0; j < K_NODES; ++j) {
            float w = WL[sp][i * K_NODES + j];
            s0 += w*xf[j][0]; s1 += w*xf[j][1]; s2 += w*xf[j][2]; s3 += w*xf[j][3];
        }
        float wi = invL[sp][i];
        uint2 r;
        r.x = (unsigned int)f2bf(s0*wi) | ((unsigned int)f2bf(s1*wi) << 16);
        r.y = (unsigned int)f2bf(s2*wi) | ((unsigned int)f2bf(s3*wi) << 16);
        *(uint2*)(aggbf + base + i * C_DIM) = r;
    }
}

// ---------------- Kernel 4: fused GEMM: relu(agg@Wm^T) + x@Wo^T ------------
// 128x128 tile, BK=32, TRIPLE-buffered LDS (48KB -> 3 blocks/CU).
// Depth-3 pipeline: step t stages tile t+2, computes tile t, and waits with
// COUNTED vmcnt(4) (raw s_barrier) so the newest stage stays in flight.
// 32 steps total: steps 0-15 = pass0 (agg@Wm, relu at 15), 16-31 = pass1.
// Swizzle: physical 16B chunk p of row r holds logical chunk p ^ ((r>>1)&3)
// -> 2-way bank aliasing on ds_read_b128 (free), linear dest for gload_lds.
#define TM 128
#define TN 128
#define BK 32

__global__ __launch_bounds__(256, 3) void gemm_fused(
    const unsigned short* __restrict__ Aagg, const unsigned short* __restrict__ Axin,
    const unsigned short* __restrict__ Bwm,  const unsigned short* __restrict__ Bwo,
    float* __restrict__ out)
{
    __shared__ unsigned short lA[3][TM * BK];   // 3 x 8 KB
    __shared__ unsigned short lB[3][TN * BK];   // 3 x 8 KB
    int tid  = threadIdx.x;
    int lane = tid & 63;
    int wave = tid >> 6;
    int wr = wave >> 1, wc = wave & 1;
    int bm = blockIdx.x * TM;
    int bn = blockIdx.y * TN;

    f32x4 acc[4][4];
    #pragma unroll
    for (int i = 0; i < 4; ++i)
        #pragma unroll
        for (int j = 0; j < 4; ++j) acc[i][j] = (f32x4){0.f, 0.f, 0.f, 0.f};

    // ds_read side: lane holds row (wr*64+i*16+lrow), k-chunk kc (8 bf16)
    int lrow = lane & 15;
    int kc   = lane >> 4;
    int pcs  = (kc ^ ((lrow >> 1) & 3)) * 8;      // physical chunk offset (elems)
    // staging side: 16 rows per wave-instruction, 4 chunks/row
    int srow = lane >> 2;                          // 0..15
    int scol = lane & 3;
    int lc   = scol ^ ((srow >> 1) & 3);          // logical chunk this lane fetches
    // per-lane global element offsets (it = 0 / 1), row-major source
    size_t goff0 = (size_t)(wave * 16 + srow) * C_DIM + lc * 8;
    size_t goff1 = goff0 + (size_t)64 * C_DIM;

#define STAGE(buf, Ap, Bp, kb)                                               \
    {                                                                         \
        async16((Ap) + (size_t)bm * C_DIM + (kb) + goff0,                     \
                &lA[buf][(wave * 16) * BK]);                                  \
        async16((Ap) + (size_t)bm * C_DIM + (kb) + goff1,                     \
                &lA[buf][(64 + wave * 16) * BK]);                             \
        async16((Bp) + (size_t)bn * C_DIM + (kb) + goff0,                     \
                &lB[buf][(wave * 16) * BK]);                                  \
        async16((Bp) + (size_t)bn * C_DIM + (kb) + goff1,                     \
                &lB[buf][(64 + wave * 16) * BK]);                             \
    }

    // prologue: stage tiles 0 and 1 (both pass 0)
    STAGE(0, Aagg, Bwm, 0);
    STAGE(1, Aagg, Bwm, BK);
    asm volatile("s_waitcnt vmcnt(4)" ::: "memory");   // tile 0 landed (mine)
    __builtin_amdgcn_s_barrier();                       // tile 0 landed (all)

    #pragma unroll 32
    for (int t = 0; t < 32; ++t) {
        // stage tile t+2 (2 steps ahead) into the buffer freed last step
        if (t + 2 < 32) {
            const unsigned short* Ap = ((t + 2) < 16) ? Aagg : Axin;
            const unsigned short* Bp = ((t + 2) < 16) ? Bwm  : Bwo;
            STAGE((t + 2) % 3, Ap, Bp, ((t + 2) & 15) * BK);
        }
        // compute tile t from buf[t%3]
        {
            const int buf = t % 3;
            bf16x8 af[4], bfr[4];
            #pragma unroll
            for (int i = 0; i < 4; ++i)
                af[i] = *(const bf16x8*)&lA[buf][(wr * 64 + i * 16 + lrow) * BK + pcs];
            #pragma unroll
            for (int j = 0; j < 4; ++j)
                bfr[j] = *(const bf16x8*)&lB[buf][(wc * 64 + j * 16 + lrow) * BK + pcs];
            __builtin_amdgcn_s_setprio(1);
            #pragma unroll
            for (int i = 0; i < 4; ++i)
                #pragma unroll
                for (int j = 0; j < 4; ++j)
                    acc[i][j] = __builtin_amdgcn_mfma_f32_16x16x32_bf16(
                        af[i], bfr[j], acc[i][j], 0, 0, 0);
            __builtin_amdgcn_s_setprio(0);
        }
        if (t == 15) {  // end of pass 0: relu before pass 1 accumulates on top
            #pragma unroll
            for (int i = 0; i < 4; ++i)
                #pragma unroll
                for (int j = 0; j < 4; ++j)
                    #pragma unroll
                    for (int r = 0; r < 4; ++r)
                        acc[i][j][r] = fmaxf(acc[i][j][r], 0.f);
        }
        // my ds_reads of buf[t%3] done (it gets overwritten at step t+1)
        asm volatile("s_waitcnt lgkmcnt(0)" ::: "memory");
        __builtin_amdgcn_sched_barrier(0);
        // counted wait: tile t+1's loads (issued at t-1) landed; tile t+2's
        // 4 loads (just issued) stay in flight across the barrier
        if (t < 30)      asm volatile("s_waitcnt vmcnt(4)" ::: "memory");
        else             asm volatile("s_waitcnt vmcnt(0)" ::: "memory");
        if (t < 31) __builtin_amdgcn_s_barrier();
    }
#undef STAGE

    int orow0 = bm + wr * 64 + (lane >> 4) * 4;
    int ocol0 = bn + wc * 64 + (lane & 15);
    #pragma unroll
    for (int i = 0; i < 4; ++i)
        #pragma unroll
        for (int j = 0; j < 4; ++j)
            #pragma unroll
            for (int r = 0; r < 4; ++r)
                out[(size_t)(orow0 + i * 16 + r) * OUT_DIM + (ocol0 + j * 16)] = acc[i][j][r];
}

extern "C" void kernel_launch(void* const* d_in, const int* in_sizes, int n_in,
                              void* d_out, int out_size, void* d_ws, size_t ws_size,
                              hipStream_t stream)
{
    const float* x     = (const float*)d_in[0];
    const float* adj   = (const float*)d_in[1];
    const int*   ei    = (const int*)d_in[2];
    const int*   ej    = (const int*)d_in[3];
    const float* gamma = (const float*)d_in[4];
    const float* beta  = (const float*)d_in[5];
    const float* wdir  = (const float*)d_in[6];
    const float* Wm    = (const float*)d_in[7];
    const float* Wo    = (const float*)d_in[8];
    float* out = (float*)d_out;

    int N = in_sizes[0] / (K_NODES * C_DIM);   // 2048
    int M = N * K_NODES;                        // 28672

    float* ws_f   = (float*)d_ws;
    float* u      = ws_f + 1024;               // [512]
    float* bpart  = ws_f + 1536;               // [8]
    float* part   = ws_f + 2048;               // [256*1024]
    char*  wsb    = (char*)d_ws;
    size_t off    = (size_t)(2048 + 256 * 1024) * sizeof(float);
    unsigned short* wmbf  = (unsigned short*)(wsb + off);  off += (size_t)OUT_DIM * C_DIM * 2;
    unsigned short* wobf  = (unsigned short*)(wsb + off);  off += (size_t)OUT_DIM * C_DIM * 2;
    unsigned short* xbf   = (unsigned short*)(wsb + off);  off += (size_t)M * C_DIM * 2;
    unsigned short* aggbf = (unsigned short*)(wsb + off);

    float inv_ne = 1.0f / ((float)N * (float)N_EDGE);

    hipLaunchKernelGGL(stats_partial, dim3(N / 8), dim3(1024), 0, stream,
                       x, part, xbf, Wm, Wo, wmbf, wobf);
    hipLaunchKernelGGL(finalize_stats, dim3(8), dim3(256), 0, stream,
                       part, inv_ne, gamma, beta, wdir, u, bpart);
    hipLaunchKernelGGL(fuse_graph, dim3(N / 2), dim3(256), 0, stream,
                       xbf, adj, ei, ej, u, bpart, aggbf);
    hipLaunchKernelGGL(gemm_fused, dim3(M / TM, OUT_DIM / TN), dim3(256), 0, stream,
                       aggbf, xbf, wmbf, wobf, out);
}

// Round 3
// 183.961 us; speedup vs baseline: 1.0085x; 1.0085x over previous
//
#include <hip/hip_runtime.h>
#include <stdint.h>

#define K_NODES 14
#define C_DIM   512
#define OUT_DIM 512
#define N_EDGE  78

typedef float  f32x4  __attribute__((ext_vector_type(4)));
typedef __bf16 bf16x8 __attribute__((ext_vector_type(8)));

__device__ __forceinline__ unsigned short f2bf(float f) {
    unsigned int u = __builtin_bit_cast(unsigned int, f);
    unsigned int r = (u + 0x7fffu + ((u >> 16) & 1u)) >> 16;  // RNE
    return (unsigned short)r;
}
__device__ __forceinline__ float bf2f(unsigned short s) {
    return __builtin_bit_cast(float, (unsigned int)s << 16);
}

// async 16B global -> LDS (LDS dest is wave-uniform base; HW adds lane*16)
__device__ __forceinline__ void async16(const void* g, void* l) {
    __builtin_amdgcn_global_load_lds(
        (const __attribute__((address_space(1))) unsigned int*)g,
        (__attribute__((address_space(3))) unsigned int*)l, 16, 0, 0);
}

// ------- Kernel 1: per-channel stats partials + x->bf16 + weights->bf16 ----
__global__ __launch_bounds__(1024) void stats_partial(
    const float* __restrict__ x, float* __restrict__ part,
    unsigned short* __restrict__ xbf,
    const float* __restrict__ Wm, const float* __restrict__ Wo,
    unsigned short* __restrict__ wmbf, unsigned short* __restrict__ wobf)
{
    int t  = threadIdx.x;
    int q  = t & 127;           // channel quad: channels 4q..4q+3
    int sn = t >> 7;            // sample slot 0..7
    int n  = blockIdx.x * 8 + sn;
    size_t base = (size_t)n * K_NODES * C_DIM + q * 4;

    f32x4 g = *(const f32x4*)(x + base + 13 * C_DIM);
    ushort4 gb; gb.x=f2bf(g.x); gb.y=f2bf(g.y); gb.z=f2bf(g.z); gb.w=f2bf(g.w);
    *(ushort4*)(xbf + base + 13 * C_DIM) = gb;

    float S10=0,S11=0,S12=0,S13=0, S20=0,S21=0,S22=0,S23=0, Sw0=0,Sw1=0,Sw2=0,Sw3=0;
    #pragma unroll
    for (int k = 0; k < 13; ++k) {
        f32x4 v = *(const f32x4*)(x + base + k * C_DIM);
        ushort4 vb; vb.x=f2bf(v.x); vb.y=f2bf(v.y); vb.z=f2bf(v.z); vb.w=f2bf(v.w);
        *(ushort4*)(xbf + base + k * C_DIM) = vb;
        float wk = (float)(12 - 2 * k);
        float d0=fabsf(v.x-g.x), d1=fabsf(v.y-g.y), d2=fabsf(v.z-g.z), d3=fabsf(v.w-g.w);
        S10+=d0; S11+=d1; S12+=d2; S13+=d3;
        S20+=d0*d0; S21+=d1*d1; S22+=d2*d2; S23+=d3*d3;
        Sw0+=wk*d0; Sw1+=wk*d1; Sw2+=wk*d2; Sw3+=wk*d3;
    }
    f32x4 as = (f32x4){15.f*Sw0, 15.f*Sw1, 15.f*Sw2, 15.f*Sw3};
    f32x4 aq = (f32x4){225.f*(13.f*S20 - S10*S10), 225.f*(13.f*S21 - S11*S11),
                       225.f*(13.f*S22 - S12*S12), 225.f*(13.f*S23 - S13*S13)};

    __shared__ f32x4 redS[8][128];
    __shared__ f32x4 redQ[8][128];
    redS[sn][q] = as;
    redQ[sn][q] = aq;
    __syncthreads();
    if (sn == 0) {
        f32x4 s = redS[0][q], z = redQ[0][q];
        #pragma unroll
        for (int r = 1; r < 8; ++r) { s += redS[r][q]; z += redQ[r][q]; }
        *(f32x4*)(part + (size_t)blockIdx.x * 1024 + q * 4)       = s;
        *(f32x4*)(part + (size_t)blockIdx.x * 1024 + 512 + q * 4) = z;
    }
    int i0 = blockIdx.x * 1024 + t;
    wmbf[i0] = f2bf(Wm[i0]);
    wobf[i0] = f2bf(Wo[i0]);
}

// ---------------- Kernel 2: finalize stats -> u[c], bpart[8] ---------------
__global__ __launch_bounds__(256) void finalize_stats(
    const float* __restrict__ part, float inv_ne,
    const float* __restrict__ gamma, const float* __restrict__ beta,
    const float* __restrict__ wdir, float* __restrict__ u, float* __restrict__ bpart)
{
    int lane = threadIdx.x & 63;
    int wv   = threadIdx.x >> 6;        // 0..3
    int c    = blockIdx.x * 64 + lane;  // channel
    float s = 0.f, q = 0.f;
    #pragma unroll 8
    for (int r = wv; r < 256; r += 4) {
        s += part[(size_t)r * 1024 + c];
        q += part[(size_t)r * 1024 + 512 + c];
    }
    __shared__ float shs[4][64], shq[4][64];
    shs[wv][lane] = s; shq[wv][lane] = q;
    __syncthreads();
    if (wv == 0) {
        s = shs[0][lane] + shs[1][lane] + shs[2][lane] + shs[3][lane];
        q = shq[0][lane] + shq[1][lane] + shq[2][lane] + shq[3][lane];
        float mean = s * inv_ne;
        float var  = q * inv_ne - mean * mean;
        float sc   = gamma[c] / sqrtf(var + 1e-5f);
        u[c] = sc * wdir[c];
        float b = (beta[c] - mean * sc) * wdir[c];
        #pragma unroll
        for (int off = 1; off < 64; off <<= 1) b += __shfl_xor(b, off, 64);
        if (lane == 0) bpart[blockIdx.x] = b;
    }
}

// ---------------- Kernel 3: per-n gates + adjacency + agg ------------------
__global__ __launch_bounds__(256) void fuse_graph(
    const unsigned short* __restrict__ xbf, const float* __restrict__ adj,
    const int* __restrict__ ei, const int* __restrict__ ej,
    const float* __restrict__ u, const float* __restrict__ bpart,
    unsigned short* __restrict__ aggbf)
{
    __shared__ float WL[2][196];
    __shared__ float Dp[2][2][13];
    __shared__ float invL[2][14];
    int wv = threadIdx.x >> 6, lane = threadIdx.x & 63;
    int sp = wv >> 1;          // sample slot 0..1
    int h  = wv & 1;           // channel half 0..1
    int n  = blockIdx.x * 2 + sp;
    size_t base = (size_t)n * K_NODES * C_DIM + h * 256 + lane * 4;

    float xf[K_NODES][4];
    #pragma unroll
    for (int k = 0; k < K_NODES; ++k) {
        uint2 raw = *(const uint2*)(xbf + base + k * C_DIM);
        xf[k][0]=bf2f(raw.x&0xffff); xf[k][1]=bf2f(raw.x>>16);
        xf[k][2]=bf2f(raw.y&0xffff); xf[k][3]=bf2f(raw.y>>16);
    }
    f32x4 uv = *(const f32x4*)(u + h * 256 + lane * 4);

    #pragma unroll
    for (int k = 0; k < 13; ++k) {
        float p = fabsf(xf[k][0]-xf[13][0])*uv.x + fabsf(xf[k][1]-xf[13][1])*uv.y
                + fabsf(xf[k][2]-xf[13][2])*uv.z + fabsf(xf[k][3]-xf[13][3])*uv.w;
        #pragma unroll
        for (int off = 1; off < 64; off <<= 1) p += __shfl_xor(p, off, 64);
        if (lane == 0) Dp[sp][h][k] = p;
    }
    __syncthreads();

    if (h == 0) {
        float bc = 0.f;
        #pragma unroll
        for (int b8 = 0; b8 < 8; ++b8) bc += bpart[b8];
        for (int e = lane; e < N_EDGE; e += 64) {
            int ii = ei[e], jj = ej[e];
            float Di = Dp[sp][0][ii] + Dp[sp][1][ii];
            float Dj = Dp[sp][0][jj] + Dp[sp][1][jj];
            float z = 4.0f * (15.f * (Di - Dj) + bc);
            float a = 1.f / (1.f + expf(-z));
            WL[sp][ii * K_NODES + jj] = adj[ii * K_NODES + jj] * (2.f * a);
            WL[sp][jj * K_NODES + ii] = adj[jj * K_NODES + ii] * (2.f * (1.f - a));
        }
    } else {
        for (int idx = lane; idx < K_NODES * K_NODES; idx += 64) {
            int i = idx / K_NODES, j = idx - i * K_NODES;
            if (i == j || i == 13 || j == 13) WL[sp][idx] = adj[idx];
        }
    }
    __syncthreads();
    if (h == 0 && lane < K_NODES) {
        float s = 0.f;
        #pragma unroll
        for (int j = 0; j < K_NODES; ++j) s += fabsf(WL[sp][lane * K_NODES + j]);
        invL[sp][lane] = 1.f / fmaxf(s, 1e-12f);
    }
    __syncthreads();

    #pragma unroll
    for (int i = 0; i < K_NODES; ++i) {
        float s0=0.f,s1=0.f,s2=0.f,s3=0.f;
        #pragma unroll
        for (int j = 0; j < K_NODES; ++j) {
            float w = WL[sp][i * K_NODES + j];
            s0 += w*xf[j][0]; s1 += w*xf[j][1]; s2 += w*xf[j][2]; s3 += w*xf[j][3];
        }
        float wi = invL[sp][i];
        uint2 r;
        r.x = (unsigned int)f2bf(s0*wi) | ((unsigned int)f2bf(s1*wi) << 16);
        r.y = (unsigned int)f2bf(s2*wi) | ((unsigned int)f2bf(s3*wi) << 16);
        *(uint2*)(aggbf + base + i * C_DIM) = r;
    }
}

// ---------------- Kernel 4: fused GEMM: relu(agg@Wm^T) + x@Wo^T ------------
// 256x128 tile, 8 waves (512 thr), BK=64, TRIPLE-buffered LDS (144 KB, 1
// block/CU, 2 waves/SIMD). Depth-3 pipeline at FULL K-tile granularity:
// step t stages tile t+2 (6 async16), computes tile t (2 ks x 16 MFMA/wave),
// then waits COUNTED vmcnt(6) so tile t+2's loads stay in flight across the
// barrier. Tile t+1's loads (issued at t-1) get ~2 steps to land -> zero
// steady-state exposure. 16 steps: 0-7 pass0 (agg@Wm, relu at 7), 8-15 pass1.
// Swizzle (same as R1, measured 0 conflicts): physical 16B chunk p of row r
// holds logical chunk p ^ (r&7); linear LDS dest for global_load_lds.
#define TM 256
#define TN 128
#define BK 64

__global__ __launch_bounds__(512, 2) void gemm_fused(
    const unsigned short* __restrict__ Aagg, const unsigned short* __restrict__ Axin,
    const unsigned short* __restrict__ Bwm,  const unsigned short* __restrict__ Bwo,
    float* __restrict__ out)
{
    __shared__ unsigned short lA[3][TM * BK];   // 3 x 32 KB
    __shared__ unsigned short lB[3][TN * BK];   // 3 x 16 KB
    int tid  = threadIdx.x;
    int lane = tid & 63;
    int wave = tid >> 6;            // 0..7
    int wr = wave >> 1;             // 0..3  (M sub-tile, 64 rows)
    int wc = wave & 1;              // 0..1  (N sub-tile, 64 cols)
    int bm = blockIdx.x * TM;
    int bn = blockIdx.y * TN;

    f32x4 acc[4][4];
    #pragma unroll
    for (int i = 0; i < 4; ++i)
        #pragma unroll
        for (int j = 0; j < 4; ++j) acc[i][j] = (f32x4){0.f, 0.f, 0.f, 0.f};

    // ds_read side
    int lrow = lane & 15;
    int xorv = lane & 7;
    // staging side: 8 lanes per row, 128B contiguous per row
    int srow = tid >> 3;                          // 0..63
    int lcu  = ((tid & 7) ^ (srow & 7)) * 8;      // logical elem offset in row

#define STAGE(buf, Ap, Bp, kb)                                               \
    {                                                                         \
        _Pragma("unroll")                                                     \
        for (int it = 0; it < 4; ++it)                                        \
            async16((Ap) + (size_t)(bm + it * 64 + srow) * C_DIM + (kb) + lcu,\
                    &lA[buf][(it * 64 + wave * 8) * BK]);                     \
        _Pragma("unroll")                                                     \
        for (int it = 0; it < 2; ++it)                                        \
            async16((Bp) + (size_t)(bn + it * 64 + srow) * C_DIM + (kb) + lcu,\
                    &lB[buf][(it * 64 + wave * 8) * BK]);                     \
    }

    // prologue: stage tiles 0 and 1 (both pass 0)
    STAGE(0, Aagg, Bwm, 0);
    STAGE(1, Aagg, Bwm, BK);
    asm volatile("s_waitcnt vmcnt(6)" ::: "memory");   // tile 0 landed (mine)
    __builtin_amdgcn_s_barrier();                       // tile 0 landed (all)

    #pragma unroll
    for (int t = 0; t < 16; ++t) {
        // stage tile t+2 into the buffer freed at the end of step t-1
        if (t + 2 < 16) {
            const unsigned short* Ap = ((t + 2) < 8) ? Aagg : Axin;
            const unsigned short* Bp = ((t + 2) < 8) ? Bwm  : Bwo;
            STAGE((t + 2) % 3, Ap, Bp, ((t + 2) & 7) * BK);
        }
        // compute tile t from buf[t%3]
        {
            const int buf = t % 3;
            #pragma unroll
            for (int ks = 0; ks < 2; ++ks) {
                int pcs = ((ks * 4 + (lane >> 4)) ^ xorv) * 8;
                bf16x8 af[4], bfr[4];
                #pragma unroll
                for (int i = 0; i < 4; ++i)
                    af[i] = *(const bf16x8*)&lA[buf][(wr * 64 + i * 16 + lrow) * BK + pcs];
                #pragma unroll
                for (int j = 0; j < 4; ++j)
                    bfr[j] = *(const bf16x8*)&lB[buf][(wc * 64 + j * 16 + lrow) * BK + pcs];
                __builtin_amdgcn_s_setprio(1);
                #pragma unroll
                for (int i = 0; i < 4; ++i)
                    #pragma unroll
                    for (int j = 0; j < 4; ++j)
                        acc[i][j] = __builtin_amdgcn_mfma_f32_16x16x32_bf16(
                            af[i], bfr[j], acc[i][j], 0, 0, 0);
                __builtin_amdgcn_s_setprio(0);
            }
        }
        if (t == 7) {  // end of pass 0: relu before pass 1 accumulates on top
            #pragma unroll
            for (int i = 0; i < 4; ++i)
                #pragma unroll
                for (int j = 0; j < 4; ++j)
                    #pragma unroll
                    for (int r = 0; r < 4; ++r)
                        acc[i][j][r] = fmaxf(acc[i][j][r], 0.f);
        }
        // my ds_reads of buf[t%3] done (overwritten by STAGE at step t+1)
        asm volatile("s_waitcnt lgkmcnt(0)" ::: "memory");
        __builtin_amdgcn_sched_barrier(0);
        // counted wait: tile t+1 landed; tile t+2's 6 loads stay in flight
        if (t < 14)      asm volatile("s_waitcnt vmcnt(6)" ::: "memory");
        else if (t == 14) asm volatile("s_waitcnt vmcnt(0)" ::: "memory");
        if (t < 15) __builtin_amdgcn_s_barrier();
    }
#undef STAGE

    int orow0 = bm + wr * 64 + (lane >> 4) * 4;
    int ocol0 = bn + wc * 64 + (lane & 15);
    #pragma unroll
    for (int i = 0; i < 4; ++i)
        #pragma unroll
        for (int j = 0; j < 4; ++j)
            #pragma unroll
            for (int r = 0; r < 4; ++r)
                out[(size_t)(orow0 + i * 16 + r) * OUT_DIM + (ocol0 + j * 16)] = acc[i][j][r];
}

extern "C" void kernel_launch(void* const* d_in, const int* in_sizes, int n_in,
                              void* d_out, int out_size, void* d_ws, size_t ws_size,
                              hipStream_t stream)
{
    const float* x     = (const float*)d_in[0];
    const float* adj   = (const float*)d_in[1];
    const int*   ei    = (const int*)d_in[2];
    const int*   ej    = (const int*)d_in[3];
    const float* gamma = (const float*)d_in[4];
    const float* beta  = (const float*)d_in[5];
    const float* wdir  = (const float*)d_in[6];
    const float* Wm    = (const float*)d_in[7];
    const float* Wo    = (const float*)d_in[8];
    float* out = (float*)d_out;

    int N = in_sizes[0] / (K_NODES * C_DIM);   // 2048
    int M = N * K_NODES;                        // 28672

    float* ws_f   = (float*)d_ws;
    float* u      = ws_f + 1024;               // [512]
    float* bpart  = ws_f + 1536;               // [8]
    float* part   = ws_f + 2048;               // [256*1024]
    char*  wsb    = (char*)d_ws;
    size_t off    = (size_t)(2048 + 256 * 1024) * sizeof(float);
    unsigned short* wmbf  = (unsigned short*)(wsb + off);  off += (size_t)OUT_DIM * C_DIM * 2;
    unsigned short* wobf  = (unsigned short*)(wsb + off);  off += (size_t)OUT_DIM * C_DIM * 2;
    unsigned short* xbf   = (unsigned short*)(wsb + off);  off += (size_t)M * C_DIM * 2;
    unsigned short* aggbf = (unsigned short*)(wsb + off);

    float inv_ne = 1.0f / ((float)N * (float)N_EDGE);

    hipLaunchKernelGGL(stats_partial, dim3(N / 8), dim3(1024), 0, stream,
                       x, part, xbf, Wm, Wo, wmbf, wobf);
    hipLaunchKernelGGL(finalize_stats, dim3(8), dim3(256), 0, stream,
                       part, inv_ne, gamma, beta, wdir, u, bpart);
    hipLaunchKernelGGL(fuse_graph, dim3(N / 2), dim3(256), 0, stream,
                       xbf, adj, ei, ej, u, bpart, aggbf);
    hipLaunchKernelGGL(gemm_fused, dim3(M / TM, OUT_DIM / TN), dim3(512), 0, stream,
                       aggbf, xbf, wmbf, wobf, out);
}

// Round 4
// 180.949 us; speedup vs baseline: 1.0253x; 1.0166x over previous
//
#include <hip/hip_runtime.h>
#include <stdint.h>

#define K_NODES 14
#define C_DIM   512
#define OUT_DIM 512
#define N_EDGE  78

typedef float  f32x4  __attribute__((ext_vector_type(4)));
typedef __bf16 bf16x8 __attribute__((ext_vector_type(8)));

__device__ __forceinline__ unsigned short f2bf(float f) {
    unsigned int u = __builtin_bit_cast(unsigned int, f);
    unsigned int r = (u + 0x7fffu + ((u >> 16) & 1u)) >> 16;  // RNE
    return (unsigned short)r;
}
__device__ __forceinline__ float bf2f(unsigned short s) {
    return __builtin_bit_cast(float, (unsigned int)s << 16);
}

// async 16B global -> LDS (LDS dest is wave-uniform base; HW adds lane*16)
__device__ __forceinline__ void async16(const void* g, void* l) {
    __builtin_amdgcn_global_load_lds(
        (const __attribute__((address_space(1))) unsigned int*)g,
        (__attribute__((address_space(3))) unsigned int*)l, 16, 0, 0);
}

// ------- Kernel 1: per-channel stats partials + x->bf16 + weights->bf16 ----
// 256 blocks x 512 thr; each thread handles TWO samples (more ILP/wave).
// part layout unchanged: 256 rows x 1024 (sum, sumsq per channel).
__global__ __launch_bounds__(512) void stats_partial(
    const float* __restrict__ x, float* __restrict__ part,
    unsigned short* __restrict__ xbf,
    const float* __restrict__ Wm, const float* __restrict__ Wo,
    unsigned short* __restrict__ wmbf, unsigned short* __restrict__ wobf)
{
    int t  = threadIdx.x;
    int q  = t & 127;           // channel quad: channels 4q..4q+3
    int sn = t >> 7;            // sample slot 0..3
    f32x4 as = (f32x4){0.f,0.f,0.f,0.f};
    f32x4 aq = (f32x4){0.f,0.f,0.f,0.f};

    #pragma unroll
    for (int half = 0; half < 2; ++half) {
        int n = blockIdx.x * 8 + half * 4 + sn;
        size_t base = (size_t)n * K_NODES * C_DIM + q * 4;

        f32x4 g = *(const f32x4*)(x + base + 13 * C_DIM);
        ushort4 gb; gb.x=f2bf(g.x); gb.y=f2bf(g.y); gb.z=f2bf(g.z); gb.w=f2bf(g.w);
        *(ushort4*)(xbf + base + 13 * C_DIM) = gb;

        float S10=0,S11=0,S12=0,S13=0, S20=0,S21=0,S22=0,S23=0, Sw0=0,Sw1=0,Sw2=0,Sw3=0;
        #pragma unroll
        for (int k = 0; k < 13; ++k) {
            f32x4 v = *(const f32x4*)(x + base + k * C_DIM);
            ushort4 vb; vb.x=f2bf(v.x); vb.y=f2bf(v.y); vb.z=f2bf(v.z); vb.w=f2bf(v.w);
            *(ushort4*)(xbf + base + k * C_DIM) = vb;
            float wk = (float)(12 - 2 * k);
            float d0=fabsf(v.x-g.x), d1=fabsf(v.y-g.y), d2=fabsf(v.z-g.z), d3=fabsf(v.w-g.w);
            S10+=d0; S11+=d1; S12+=d2; S13+=d3;
            S20+=d0*d0; S21+=d1*d1; S22+=d2*d2; S23+=d3*d3;
            Sw0+=wk*d0; Sw1+=wk*d1; Sw2+=wk*d2; Sw3+=wk*d3;
        }
        as += (f32x4){15.f*Sw0, 15.f*Sw1, 15.f*Sw2, 15.f*Sw3};
        aq += (f32x4){225.f*(13.f*S20 - S10*S10), 225.f*(13.f*S21 - S11*S11),
                      225.f*(13.f*S22 - S12*S12), 225.f*(13.f*S23 - S13*S13)};
    }

    __shared__ f32x4 redS[4][128];
    __shared__ f32x4 redQ[4][128];
    redS[sn][q] = as;
    redQ[sn][q] = aq;
    __syncthreads();
    if (sn == 0) {
        f32x4 s = redS[0][q], z = redQ[0][q];
        #pragma unroll
        for (int r = 1; r < 4; ++r) { s += redS[r][q]; z += redQ[r][q]; }
        *(f32x4*)(part + (size_t)blockIdx.x * 1024 + q * 4)       = s;
        *(f32x4*)(part + (size_t)blockIdx.x * 1024 + 512 + q * 4) = z;
    }
    // weight conversion: 1024 elems of each matrix per block, 2 per thread
    int i0 = blockIdx.x * 1024 + t;
    wmbf[i0] = f2bf(Wm[i0]);
    wobf[i0] = f2bf(Wo[i0]);
    wmbf[i0 + 512] = f2bf(Wm[i0 + 512]);
    wobf[i0 + 512] = f2bf(Wo[i0 + 512]);
}

// ---------------- Kernel 2: finalize stats -> u[c], bpart[8] ---------------
__global__ __launch_bounds__(256) void finalize_stats(
    const float* __restrict__ part, float inv_ne,
    const float* __restrict__ gamma, const float* __restrict__ beta,
    const float* __restrict__ wdir, float* __restrict__ u, float* __restrict__ bpart)
{
    int lane = threadIdx.x & 63;
    int wv   = threadIdx.x >> 6;        // 0..3
    int c    = blockIdx.x * 64 + lane;  // channel
    float s = 0.f, q = 0.f;
    #pragma unroll 8
    for (int r = wv; r < 256; r += 4) {
        s += part[(size_t)r * 1024 + c];
        q += part[(size_t)r * 1024 + 512 + c];
    }
    __shared__ float shs[4][64], shq[4][64];
    shs[wv][lane] = s; shq[wv][lane] = q;
    __syncthreads();
    if (wv == 0) {
        s = shs[0][lane] + shs[1][lane] + shs[2][lane] + shs[3][lane];
        q = shq[0][lane] + shq[1][lane] + shq[2][lane] + shq[3][lane];
        float mean = s * inv_ne;
        float var  = q * inv_ne - mean * mean;
        float sc   = gamma[c] / sqrtf(var + 1e-5f);
        u[c] = sc * wdir[c];
        float b = (beta[c] - mean * sc) * wdir[c];
        #pragma unroll
        for (int off = 1; off < 64; off <<= 1) b += __shfl_xor(b, off, 64);
        if (lane == 0) bpart[blockIdx.x] = b;
    }
}

// ---------------- Kernel 3: per-n gates + adjacency + agg ------------------
// ONE wave per sample (lane owns 8 channels, 16B loads). 4 samples per
// 256-thr block; everything per-sample is wave-internal -> NO barriers.
// D kept in LDS (runtime-indexed by edge list; regs would go to scratch).
__global__ __launch_bounds__(256) void fuse_graph(
    const unsigned short* __restrict__ xbf, const float* __restrict__ adj,
    const int* __restrict__ ei, const int* __restrict__ ej,
    const float* __restrict__ u, const float* __restrict__ bpart,
    unsigned short* __restrict__ aggbf)
{
    __shared__ float WL[4][196];
    __shared__ float Dsh[4][13];
    __shared__ float invW[4][14];
    int wv = threadIdx.x >> 6, lane = threadIdx.x & 63;
    int n  = blockIdx.x * 4 + wv;
    size_t base = (size_t)n * K_NODES * C_DIM + lane * 8;

    // load 14 x-rows (8 bf16 = 16B each) and convert to fp32
    float xf[K_NODES][8];
    #pragma unroll
    for (int k = 0; k < K_NODES; ++k) {
        uint4 raw = *(const uint4*)(xbf + base + k * C_DIM);
        xf[k][0]=bf2f(raw.x&0xffff); xf[k][1]=bf2f(raw.x>>16);
        xf[k][2]=bf2f(raw.y&0xffff); xf[k][3]=bf2f(raw.y>>16);
        xf[k][4]=bf2f(raw.z&0xffff); xf[k][5]=bf2f(raw.z>>16);
        xf[k][6]=bf2f(raw.w&0xffff); xf[k][7]=bf2f(raw.w>>16);
    }
    float uvv[8];
    {
        f32x4 a = *(const f32x4*)(u + lane * 8);
        f32x4 b = *(const f32x4*)(u + lane * 8 + 4);
        uvv[0]=a.x; uvv[1]=a.y; uvv[2]=a.z; uvv[3]=a.w;
        uvv[4]=b.x; uvv[5]=b.y; uvv[6]=b.z; uvv[7]=b.w;
    }

    // D_k = sum_c |x[k][c]-x[13][c]| * u[c]  (full-wave butterfly)
    #pragma unroll
    for (int k = 0; k < 13; ++k) {
        float p = 0.f;
        #pragma unroll
        for (int c = 0; c < 8; ++c) p += fabsf(xf[k][c]-xf[13][c])*uvv[c];
        #pragma unroll
        for (int off = 1; off < 64; off <<= 1) p += __shfl_xor(p, off, 64);
        if (lane == 0) Dsh[wv][k] = p;
    }

    // non-edge entries keep adj value (i==j or i==13 or j==13)
    #pragma unroll
    for (int r = 0; r < 4; ++r) {
        int idx = r * 64 + lane;
        if (idx < K_NODES * K_NODES) {
            int i = idx / K_NODES, j = idx - i * K_NODES;
            if (i == j || i == 13 || j == 13) WL[wv][idx] = adj[idx];
        }
    }
    float bc = 0.f;
    #pragma unroll
    for (int b8 = 0; b8 < 8; ++b8) bc += bpart[b8];
    // edge gates: e = lane, then e = 64+lane (lane<14)
    #pragma unroll
    for (int r = 0; r < 2; ++r) {
        int e = r * 64 + lane;
        if (e < N_EDGE) {
            int ii = ei[e], jj = ej[e];
            float z = 4.0f * (15.f * (Dsh[wv][ii] - Dsh[wv][jj]) + bc);
            float a = 1.f / (1.f + expf(-z));
            WL[wv][ii * K_NODES + jj] = adj[ii * K_NODES + jj] * (2.f * a);
            WL[wv][jj * K_NODES + ii] = adj[jj * K_NODES + ii] * (2.f * (1.f - a));
        }
    }
    // row norms (wave-internal; LDS ops are in-order within a wave)
    if (lane < K_NODES) {
        float s = 0.f;
        #pragma unroll
        for (int j = 0; j < K_NODES; ++j) s += fabsf(WL[wv][lane * K_NODES + j]);
        invW[wv][lane] = 1.f / fmaxf(s, 1e-12f);
    }

    // agg[i][c] = inv[i] * sum_j W[i][j] * x[j][c]   (8 channels per lane)
    #pragma unroll
    for (int i = 0; i < K_NODES; ++i) {
        float s0=0,s1=0,s2=0,s3=0,s4=0,s5=0,s6=0,s7=0;
        #pragma unroll
        for (int j = 0; j < K_NODES; ++j) {
            float w = WL[wv][i * K_NODES + j];
            s0+=w*xf[j][0]; s1+=w*xf[j][1]; s2+=w*xf[j][2]; s3+=w*xf[j][3];
            s4+=w*xf[j][4]; s5+=w*xf[j][5]; s6+=w*xf[j][6]; s7+=w*xf[j][7];
        }
        float wi = invW[wv][i];
        uint4 r;
        r.x = (unsigned int)f2bf(s0*wi) | ((unsigned int)f2bf(s1*wi) << 16);
        r.y = (unsigned int)f2bf(s2*wi) | ((unsigned int)f2bf(s3*wi) << 16);
        r.z = (unsigned int)f2bf(s4*wi) | ((unsigned int)f2bf(s5*wi) << 16);
        r.w = (unsigned int)f2bf(s6*wi) | ((unsigned int)f2bf(s7*wi) << 16);
        *(uint4*)(aggbf + base + i * C_DIM) = r;
    }
}

// ---------------- Kernel 4: fused GEMM: relu(agg@Wm^T) + x@Wo^T ------------
// R1 structure (best timed: 48.2us): 128x128 tile, BK=64, double-buffered
// LDS (64KB, 2 blocks/CU), depth-2 prefetch, one barrier per phase.
// NEW: bijective XCD swizzle -- the 4 blocks sharing an A-panel (same bm,
// 4 bn values) run consecutively on the SAME XCD -> A re-reads hit local L2.
#define TM 128
#define TN 128
#define BK 64

__global__ __launch_bounds__(256) void gemm_fused(
    const unsigned short* __restrict__ Aagg, const unsigned short* __restrict__ Axin,
    const unsigned short* __restrict__ Bwm,  const unsigned short* __restrict__ Bwo,
    float* __restrict__ out)
{
    __shared__ unsigned short lA[2][TM * BK];   // 2 x 16 KB
    __shared__ unsigned short lB[2][TN * BK];   // 2 x 16 KB
    int tid  = threadIdx.x;
    int lane = tid & 63;
    int wave = tid >> 6;
    int wr = wave >> 1, wc = wave & 1;
    // XCD swizzle: 896 blocks, 8 XCDs, 112 per XCD; within an XCD bn is
    // fastest so the 4 consumers of one A-panel are temporally adjacent.
    int lin = blockIdx.x;
    int g   = (lin & 7) * 112 + (lin >> 3);
    int bm  = (g >> 2) * TM;
    int bn  = (g & 3)  * TN;

    f32x4 acc[4][4];
    #pragma unroll
    for (int i = 0; i < 4; ++i)
        #pragma unroll
        for (int j = 0; j < 4; ++j) acc[i][j] = (f32x4){0.f, 0.f, 0.f, 0.f};

    int lrow = lane & 15;
    int xorv = lane & 7;
    int srow  = tid >> 3;
    int lcu   = ((tid & 7) ^ (srow & 7)) * 8;

#define STAGE(buf, Ap, Bp, kb)                                              \
    _Pragma("unroll")                                                        \
    for (int it = 0; it < 4; ++it) {                                         \
        int row = it * 32 + srow;                                            \
        async16((Ap) + (size_t)(bm + row) * C_DIM + (kb) + lcu,              \
                &lA[buf][(it * 256 + wave * 64) * 8]);                       \
        async16((Bp) + (size_t)(bn + row) * C_DIM + (kb) + lcu,              \
                &lB[buf][(it * 256 + wave * 64) * 8]);                       \
    }

    // prologue: stage phase 0 (pass 0, kb 0)
    STAGE(0, Aagg, Bwm, 0);
    __syncthreads();

    #pragma unroll
    for (int ph = 0; ph < 16; ++ph) {
        const int cur = ph & 1;
        // prefetch next phase into the other buffer (overlaps compute below)
        if (ph < 15) {
            const unsigned short* Ap = ((ph + 1) < 8) ? Aagg : Axin;
            const unsigned short* Bp = ((ph + 1) < 8) ? Bwm  : Bwo;
            STAGE(cur ^ 1, Ap, Bp, ((ph + 1) & 7) * BK);
        }
        // compute current phase from lA[cur]/lB[cur]
        #pragma unroll
        for (int ks = 0; ks < 2; ++ks) {
            int pchunk = ((ks * 4 + (lane >> 4)) ^ xorv) * 8;
            bf16x8 af[4], bfr[4];
            #pragma unroll
            for (int i = 0; i < 4; ++i)
                af[i] = *(const bf16x8*)&lA[cur][(wr * 64 + i * 16 + lrow) * BK + pchunk];
            #pragma unroll
            for (int j = 0; j < 4; ++j)
                bfr[j] = *(const bf16x8*)&lB[cur][(wc * 64 + j * 16 + lrow) * BK + pchunk];
            #pragma unroll
            for (int i = 0; i < 4; ++i)
                #pragma unroll
                for (int j = 0; j < 4; ++j)
                    acc[i][j] = __builtin_amdgcn_mfma_f32_16x16x32_bf16(
                        af[i], bfr[j], acc[i][j], 0, 0, 0);
        }
        if (ph == 7) {  // end of pass 0: relu before pass 1 accumulates on top
            #pragma unroll
            for (int i = 0; i < 4; ++i)
                #pragma unroll
                for (int j = 0; j < 4; ++j)
                    #pragma unroll
                    for (int r = 0; r < 4; ++r)
                        acc[i][j][r] = fmaxf(acc[i][j][r], 0.f);
        }
        __syncthreads();   // drains prefetch (vmcnt) + closes ds_reads on cur
    }
#undef STAGE

    int orow0 = bm + wr * 64 + (lane >> 4) * 4;
    int ocol0 = bn + wc * 64 + (lane & 15);
    #pragma unroll
    for (int i = 0; i < 4; ++i)
        #pragma unroll
        for (int j = 0; j < 4; ++j)
            #pragma unroll
            for (int r = 0; r < 4; ++r)
                out[(size_t)(orow0 + i * 16 + r) * OUT_DIM + (ocol0 + j * 16)] = acc[i][j][r];
}

extern "C" void kernel_launch(void* const* d_in, const int* in_sizes, int n_in,
                              void* d_out, int out_size, void* d_ws, size_t ws_size,
                              hipStream_t stream)
{
    const float* x     = (const float*)d_in[0];
    const float* adj   = (const float*)d_in[1];
    const int*   ei    = (const int*)d_in[2];
    const int*   ej    = (const int*)d_in[3];
    const float* gamma = (const float*)d_in[4];
    const float* beta  = (const float*)d_in[5];
    const float* wdir  = (const float*)d_in[6];
    const float* Wm    = (const float*)d_in[7];
    const float* Wo    = (const float*)d_in[8];
    float* out = (float*)d_out;

    int N = in_sizes[0] / (K_NODES * C_DIM);   // 2048
    int M = N * K_NODES;                        // 28672

    float* ws_f   = (float*)d_ws;
    float* u      = ws_f + 1024;               // [512]
    float* bpart  = ws_f + 1536;               // [8]
    float* part   = ws_f + 2048;               // [256*1024]
    char*  wsb    = (char*)d_ws;
    size_t off    = (size_t)(2048 + 256 * 1024) * sizeof(float);
    unsigned short* wmbf  = (unsigned short*)(wsb + off);  off += (size_t)OUT_DIM * C_DIM * 2;
    unsigned short* wobf  = (unsigned short*)(wsb + off);  off += (size_t)OUT_DIM * C_DIM * 2;
    unsigned short* xbf   = (unsigned short*)(wsb + off);  off += (size_t)M * C_DIM * 2;
    unsigned short* aggbf = (unsigned short*)(wsb + off);

    float inv_ne = 1.0f / ((float)N * (float)N_EDGE);

    hipLaunchKernelGGL(stats_partial, dim3(N / 8), dim3(512), 0, stream,
                       x, part, xbf, Wm, Wo, wmbf, wobf);
    hipLaunchKernelGGL(finalize_stats, dim3(8), dim3(256), 0, stream,
                       part, inv_ne, gamma, beta, wdir, u, bpart);
    hipLaunchKernelGGL(fuse_graph, dim3(N / 4), dim3(256), 0, stream,
                       xbf, adj, ei, ej, u, bpart, aggbf);
    hipLaunchKernelGGL(gemm_fused, dim3((M / TM) * (OUT_DIM / TN)), dim3(256), 0, stream,
                       aggbf, xbf, wmbf, wobf, out);
}